// Round 2
// baseline (608.685 us; speedup 1.0000x reference)
//
#include <hip/hip_runtime.h>
#include <hip/hip_bf16.h>
#include <math.h>

// Problem constants (match reference)
#define B_    512
#define C_    2048
#define HW_   48      // 8*6 spatial
#define HID_  128
#define NATTR_ 51
#define EPS_  1e-5f

// ---------------------------------------------------------------------------
// Kernel A: fused elementwise (body*A*face) -> spatial max  AND  spatial mean
// of body.  Rows = B*C = 1,048,576, each row = 48 contiguous floats.
// 64 rows per block, 256 threads, each thread 3 float4 per tensor -> fully
// coalesced 16B/lane streaming of the two 201 MB tensors.
// Key fusion: feat = body + front*gate (broadcast over spatial), so
// mean_spatial(feat) = mean_spatial(body) + front*gate -- the second pass
// over the 201 MB body tensor in the reference disappears.
// ---------------------------------------------------------------------------
__global__ __launch_bounds__(256) void fused_pool(
    const float* __restrict__ body, const float* __restrict__ face,
    const float* __restrict__ A, float* __restrict__ pooled,
    float* __restrict__ bmean) {
  __shared__ float smax[768];
  __shared__ float ssum[768];
  const int t = threadIdx.x;
  const int base_f4 = blockIdx.x * 768;        // float4 units; < 2^31
  const int c_base = (blockIdx.x & 31) * 64;   // C=2048, 64 rows/block -> period 32
  const float4* __restrict__ b4 = (const float4*)body;
  const float4* __restrict__ f4 = (const float4*)face;
  const float4* __restrict__ a4 = (const float4*)A;
#pragma unroll
  for (int j = 0; j < 3; ++j) {
    const int fl = t + 256 * j;   // 0..767
    const int rl = fl / 12;       // local row 0..63
    const int p = fl % 12;        // float4 within row
    float4 vb = b4[base_f4 + fl];
    float4 vf = f4[base_f4 + fl];
    float4 va = a4[(c_base + rl) * 12 + p];
    float m0 = vb.x * va.x * vf.x;
    float m1 = vb.y * va.y * vf.y;
    float m2 = vb.z * va.z * vf.z;
    float m3 = vb.w * va.w * vf.w;
    smax[fl] = fmaxf(fmaxf(m0, m1), fmaxf(m2, m3));
    ssum[fl] = (vb.x + vb.y) + (vb.z + vb.w);
  }
  __syncthreads();
  if (t < 64) {
    float m = -INFINITY, s = 0.f;
#pragma unroll
    for (int p = 0; p < 12; ++p) {
      m = fmaxf(m, smax[t * 12 + p]);
      s += ssum[t * 12 + p];
    }
    const int row = blockIdx.x * 64 + t;       // < 2^20
    pooled[row] = m;
    bmean[row] = s * (1.0f / 48.0f);
  }
}

// ---------------------------------------------------------------------------
// Kernel B1: h[s][o] = relu(b1[o] + sum_k pooled[s][k] * W1[o][k])
// grid = 32 sample-tiles(16) x 8 out-tiles(16) = 256 blocks, 256 threads.
// thread: s = st*16 + (t&15), o = ot*16 + (t>>4).  W1 rows broadcast across
// 16 lanes.  4 independent accumulators break the FMA dependency chain
// (latency-bound at 1 wave/SIMD occupancy).
// ---------------------------------------------------------------------------
__global__ __launch_bounds__(256) void mlp1(
    const float* __restrict__ pooled, const float* __restrict__ W1,
    const float* __restrict__ b1, float* __restrict__ h) {
  const int t = threadIdx.x;
  const int st = blockIdx.x & 31, ot = blockIdx.x >> 5;
  const int s = st * 16 + (t & 15);
  const int o = ot * 16 + (t >> 4);
  const float4* __restrict__ p4 = (const float4*)(pooled + s * C_);
  const float4* __restrict__ w4 = (const float4*)(W1 + o * C_);
  float a0 = 0.f, a1 = 0.f, a2 = 0.f, a3 = 0.f;
#pragma unroll 4
  for (int k = 0; k < C_ / 16; ++k) {
    float4 pa = p4[4 * k + 0], wa = w4[4 * k + 0];
    float4 pb = p4[4 * k + 1], wb = w4[4 * k + 1];
    float4 pc = p4[4 * k + 2], wc = w4[4 * k + 2];
    float4 pd = p4[4 * k + 3], wd = w4[4 * k + 3];
    a0 += pa.x * wa.x + pa.y * wa.y + pa.z * wa.z + pa.w * wa.w;
    a1 += pb.x * wb.x + pb.y * wb.y + pb.z * wb.z + pb.w * wb.w;
    a2 += pc.x * wc.x + pc.y * wc.y + pc.z * wc.z + pc.w * wc.w;
    a3 += pd.x * wd.x + pd.y * wd.y + pd.z * wd.z + pd.w * wd.w;
  }
  h[s * HID_ + o] = fmaxf(((a0 + a1) + (a2 + a3)) + b1[o], 0.f);
}

// ---------------------------------------------------------------------------
// Kernel B2: gap[s][c] = bmean[s][c] + front[s]*sigmoid(b2[c] + h[s].W2[c])
// grid = 32 sample-tiles(16) x 8 c-tiles(256) = 256 blocks, 256 threads.
// h tile staged in LDS; 4 accumulators for ILP.
// ---------------------------------------------------------------------------
__global__ __launch_bounds__(256) void mlp2(
    const float* __restrict__ h, const float* __restrict__ W2,
    const float* __restrict__ b2, const float* __restrict__ bmean,
    const int* __restrict__ pose, float* __restrict__ gap) {
  __shared__ float hs[16 * HID_];   // 8 KB
  const int t = threadIdx.x;
  const int st = blockIdx.x & 31, ct = blockIdx.x >> 5;
  const int s0 = st * 16;
  // load 16 h rows (2048 floats = 512 float4)
  ((float4*)hs)[t] = ((const float4*)(h + s0 * HID_))[t];
  ((float4*)hs)[t + 256] = ((const float4*)(h + s0 * HID_))[t + 256];
  __syncthreads();
  const int s_l = t >> 4;
  const int s = s0 + s_l;
  const float fr = (pose[s] == 1) ? 1.f : 0.f;
  const float4* __restrict__ h4 = (const float4*)(hs + s_l * HID_);
  for (int ci = 0; ci < 16; ++ci) {
    const int c = ct * 256 + (t & 15) + 16 * ci;
    const float4* __restrict__ w4 = (const float4*)(W2 + c * HID_);
    float a0 = 0.f, a1 = 0.f, a2 = 0.f, a3 = 0.f;
#pragma unroll
    for (int k = 0; k < HID_ / 16; ++k) {
      float4 pa = h4[4 * k + 0], wa = w4[4 * k + 0];
      float4 pb = h4[4 * k + 1], wb = w4[4 * k + 1];
      float4 pc = h4[4 * k + 2], wc = w4[4 * k + 2];
      float4 pd = h4[4 * k + 3], wd = w4[4 * k + 3];
      a0 += pa.x * wa.x + pa.y * wa.y + pa.z * wa.z + pa.w * wa.w;
      a1 += pb.x * wb.x + pb.y * wb.y + pb.z * wb.z + pb.w * wb.w;
      a2 += pc.x * wc.x + pc.y * wc.y + pc.z * wc.z + pc.w * wc.w;
      a3 += pd.x * wd.x + pd.y * wd.y + pd.z * wd.z + pd.w * wd.w;
    }
    const float acc = (a0 + a1) + (a2 + a3);
    const float g = 1.f / (1.f + expf(-(acc + b2[c])));
    gap[s * C_ + c] = bmean[s * C_ + c] + fr * g;
  }
}

// ---------------------------------------------------------------------------
// Kernel B3: z[s][o] = bl[o] + sum_k gap[s][k]*Wl[o][k]
// 128 blocks x 4 samples; 256 threads: o = t&63 (51 active), kc = t>>6 over
// 4 k-chunks of 512; cross-wave combine via LDS.  4 accumulators for ILP.
// ---------------------------------------------------------------------------
__global__ __launch_bounds__(256) void logits(
    const float* __restrict__ gap, const float* __restrict__ Wl,
    const float* __restrict__ bl, float* __restrict__ z) {
  __shared__ float gs[4 * C_];     // 32 KB
  __shared__ float part[4 * 64];   // [kc][o]
  const int t = threadIdx.x;
  const int s0 = blockIdx.x * 4;
  const float4* __restrict__ g4 = (const float4*)(gap + s0 * C_);
#pragma unroll
  for (int i = 0; i < 8; ++i) ((float4*)gs)[t + 256 * i] = g4[t + 256 * i];
  __syncthreads();
  const int o = t & 63;
  const int kc = t >> 6;
  const int orow = (o < NATTR_) ? o : (NATTR_ - 1);   // clamp: avoid OOB Wl read
  const float4* __restrict__ w4 = (const float4*)(Wl + orow * C_ + kc * 512);
  for (int si = 0; si < 4; ++si) {
    const float4* __restrict__ gg = (const float4*)(gs + si * C_ + kc * 512);
    float a0 = 0.f, a1 = 0.f, a2 = 0.f, a3 = 0.f;
#pragma unroll 2
    for (int k = 0; k < 32; ++k) {
      float4 pa = gg[4 * k + 0], wa = w4[4 * k + 0];
      float4 pb = gg[4 * k + 1], wb = w4[4 * k + 1];
      float4 pc = gg[4 * k + 2], wc = w4[4 * k + 2];
      float4 pd = gg[4 * k + 3], wd = w4[4 * k + 3];
      a0 += pa.x * wa.x + pa.y * wa.y + pa.z * wa.z + pa.w * wa.w;
      a1 += pb.x * wb.x + pb.y * wb.y + pb.z * wb.z + pb.w * wb.w;
      a2 += pc.x * wc.x + pc.y * wc.y + pc.z * wc.z + pc.w * wc.w;
      a3 += pd.x * wd.x + pd.y * wd.y + pd.z * wd.z + pd.w * wd.w;
    }
    part[kc * 64 + o] = (a0 + a1) + (a2 + a3);
    __syncthreads();
    if (t < NATTR_) {
      float v = part[t] + part[64 + t] + part[128 + t] + part[192 + t];
      z[(s0 + si) * NATTR_ + t] = v + bl[t];
    }
    __syncthreads();
  }
}

// ---------------------------------------------------------------------------
// Kernel C: BatchNorm1d (training-mode batch stats, biased variance)
// grid = 51 blocks (one per attr), 512 threads (one per batch element).
// ---------------------------------------------------------------------------
__global__ __launch_bounds__(512) void bn_kernel(
    const float* __restrict__ z, const float* __restrict__ gamma,
    const float* __restrict__ beta, float* __restrict__ out) {
  const int c = blockIdx.x;
  const int t = threadIdx.x;
  const float v = z[t * NATTR_ + c];
  float a = v, b = v * v;
#pragma unroll
  for (int off = 32; off; off >>= 1) {
    a += __shfl_down(a, off);
    b += __shfl_down(b, off);
  }
  __shared__ float s1[8], s2[8];
  const int w = t >> 6;
  if ((t & 63) == 0) { s1[w] = a; s2[w] = b; }
  __syncthreads();
  __shared__ float mu_s, inv_s;
  if (t == 0) {
    float S = 0.f, Q = 0.f;
#pragma unroll
    for (int i = 0; i < 8; ++i) { S += s1[i]; Q += s2[i]; }
    const float m = S * (1.0f / B_);
    const float var = Q * (1.0f / B_) - m * m;
    mu_s = m;
    inv_s = 1.0f / sqrtf(var + EPS_);
  }
  __syncthreads();
  out[t * NATTR_ + c] = gamma[c] * (v - mu_s) * inv_s + beta[c];
}

// ---------------------------------------------------------------------------
extern "C" void kernel_launch(void* const* d_in, const int* in_sizes, int n_in,
                              void* d_out, int out_size, void* d_ws,
                              size_t ws_size, hipStream_t stream) {
  const float* body = (const float*)d_in[0];
  const float* face = (const float*)d_in[1];
  const int* pose = (const int*)d_in[2];
  const float* A = (const float*)d_in[3];
  const float* W1 = (const float*)d_in[4];
  const float* b1 = (const float*)d_in[5];
  const float* W2 = (const float*)d_in[6];
  const float* b2 = (const float*)d_in[7];
  const float* Wl = (const float*)d_in[8];
  const float* bl = (const float*)d_in[9];
  const float* gamma = (const float*)d_in[10];
  const float* beta = (const float*)d_in[11];
  float* out = (float*)d_out;

  float* ws = (float*)d_ws;
  float* pooled = ws;                       // [512][2048]
  float* bmean = pooled + B_ * C_;          // [512][2048]
  float* h = bmean + B_ * C_;               // [512][128]
  float* gap = h + B_ * HID_;               // [512][2048]
  float* z = gap + B_ * C_;                 // [512][51]

  fused_pool<<<dim3(B_ * C_ / 64), dim3(256), 0, stream>>>(body, face, A,
                                                           pooled, bmean);
  mlp1<<<dim3(256), dim3(256), 0, stream>>>(pooled, W1, b1, h);
  mlp2<<<dim3(256), dim3(256), 0, stream>>>(h, W2, b2, bmean, pose, gap);
  logits<<<dim3(128), dim3(256), 0, stream>>>(gap, Wl, bl, z);
  bn_kernel<<<dim3(NATTR_), dim3(512), 0, stream>>>(z, gamma, beta, out);
}

// Round 3
// 505.757 us; speedup vs baseline: 1.2035x; 1.2035x over previous
//
#include <hip/hip_runtime.h>
#include <hip/hip_bf16.h>
#include <math.h>

#define B_    512
#define C_    2048
#define HW_   48      // 8*6 spatial
#define HID_  128
#define NATTR_ 51
#define EPS_  1e-5f

// ---------------------------------------------------------------------------
// Kernel A: fused (body*A*face)->spatial max  AND  spatial mean of body.
// 256 rows/block (4096 blocks), 256 threads, 12 float4/thread/tensor.
// Loads batched 6-deep in registers for memory-level parallelism.
// LDS pitch 13 (stride coprime 32) -> conflict-free tail reduce with ALL
// 256 threads active.  feat = body + front*gate broadcast => second pass
// over body replaced by mean_spatial(body) computed here.
// ---------------------------------------------------------------------------
__global__ __launch_bounds__(256) void fused_pool(
    const float* __restrict__ body, const float* __restrict__ face,
    const float* __restrict__ A, float* __restrict__ pooled,
    float* __restrict__ bmean) {
  __shared__ float smax[256 * 13];
  __shared__ float ssum[256 * 13];
  const int t = threadIdx.x;
  const int base_f4 = blockIdx.x * 3072;     // 4096*3072 < 2^31
  const int cb12 = (blockIdx.x & 7) * 3072;  // A offset (float4 units)
  const float4* __restrict__ b4 = (const float4*)body;
  const float4* __restrict__ f4 = (const float4*)face;
  const float4* __restrict__ a4 = (const float4*)A;
#pragma unroll
  for (int half = 0; half < 2; ++half) {
    float4 vb[6], vf[6], va[6];
#pragma unroll
    for (int j = 0; j < 6; ++j) {
      const int fl = t + 256 * (half * 6 + j);
      vb[j] = b4[base_f4 + fl];
      vf[j] = f4[base_f4 + fl];
      va[j] = a4[cb12 + fl];
    }
#pragma unroll
    for (int j = 0; j < 6; ++j) {
      const int fl = t + 256 * (half * 6 + j);
      const int rl = fl / 12, p = fl % 12;
      const float m0 = vb[j].x * va[j].x * vf[j].x;
      const float m1 = vb[j].y * va[j].y * vf[j].y;
      const float m2 = vb[j].z * va[j].z * vf[j].z;
      const float m3 = vb[j].w * va[j].w * vf[j].w;
      smax[rl * 13 + p] = fmaxf(fmaxf(m0, m1), fmaxf(m2, m3));
      ssum[rl * 13 + p] = (vb[j].x + vb[j].y) + (vb[j].z + vb[j].w);
    }
  }
  __syncthreads();
  float m = -INFINITY, s = 0.f;
#pragma unroll
  for (int p = 0; p < 12; ++p) {
    m = fmaxf(m, smax[t * 13 + p]);
    s += ssum[t * 13 + p];
  }
  const int row = blockIdx.x * 256 + t;
  pooled[row] = m;
  bmean[row] = s * (1.0f / 48.0f);
}

// ---------------------------------------------------------------------------
// Kernel B1: h = relu(pooled @ W1^T + b1).  K=2048 along lanes (coalesced
// 256B loads), each wave computes an 8s x 8o register tile, shfl_down
// reduce, lane 0 stores.  grid 256 blocks x 4 waves.
// ---------------------------------------------------------------------------
__global__ __launch_bounds__(256) void mlp1(
    const float* __restrict__ pooled, const float* __restrict__ W1,
    const float* __restrict__ b1, float* __restrict__ h) {
  const int t = threadIdx.x;
  const int lane = t & 63;
  const int w = t >> 6;
  const int sg = blockIdx.x >> 2;            // 0..63
  const int og = (blockIdx.x & 3) * 4 + w;   // 0..15
  const int s0 = sg * 8, o0 = og * 8;
  float acc[8][8] = {};
  const float* __restrict__ pb = pooled + lane;
  const float* __restrict__ wb = W1 + lane;
  for (int kc = 0; kc < 32; ++kc) {
    const int k = kc * 64;
    float p[8], wv[8];
#pragma unroll
    for (int i = 0; i < 8; ++i) p[i] = pb[(s0 + i) * C_ + k];
#pragma unroll
    for (int j = 0; j < 8; ++j) wv[j] = wb[(o0 + j) * C_ + k];
#pragma unroll
    for (int i = 0; i < 8; ++i)
#pragma unroll
      for (int j = 0; j < 8; ++j) acc[i][j] += p[i] * wv[j];
  }
#pragma unroll
  for (int d = 32; d >= 1; d >>= 1)
#pragma unroll
    for (int i = 0; i < 8; ++i)
#pragma unroll
      for (int j = 0; j < 8; ++j) acc[i][j] += __shfl_down(acc[i][j], d);
  if (lane == 0) {
#pragma unroll
    for (int i = 0; i < 8; ++i)
#pragma unroll
      for (int j = 0; j < 8; ++j)
        h[(s0 + i) * HID_ + o0 + j] = fmaxf(acc[i][j] + b1[o0 + j], 0.f);
  }
}

// ---------------------------------------------------------------------------
// Kernel B2: gap = bmean + front*sigmoid(h @ W2^T + b2).  W2 c-tile (128
// rows x 128 k) staged in LDS coalesced, pitch 144 floats (16B aligned,
// 2-way banks = free).  Lanes along c -> bmean/gap coalesced; h rows are
// wave-broadcast float4 (L1 resident).  grid 16 c-tiles x 16 s-tiles.
// ---------------------------------------------------------------------------
__global__ __launch_bounds__(256) void mlp2(
    const float* __restrict__ h, const float* __restrict__ W2,
    const float* __restrict__ b2, const float* __restrict__ bmean,
    const int* __restrict__ pose, float* __restrict__ gap) {
  extern __shared__ float w2s[];   // 128 * 144 floats = 73728 B
  const int t = threadIdx.x;
  const int ct = blockIdx.x & 15, st = blockIdx.x >> 4;
  const int c0 = ct * 128, s_base = st * 32;
  const float4* __restrict__ wg = (const float4*)(W2 + c0 * HID_);
#pragma unroll
  for (int r = 0; r < 16; ++r) {
    const int f = t + 256 * r;               // contiguous 16 KB chunk
    const int row = f >> 5, col4 = f & 31;
    *(float4*)&w2s[row * 144 + col4 * 4] = wg[f];
  }
  __syncthreads();
  const int c_l = t & 127, sh = t >> 7;
  const int c = c0 + c_l;
  const float bias = b2[c];
  const float* __restrict__ wrow = &w2s[c_l * 144];
  for (int si = 0; si < 16; ++si) {
    const int s = s_base + sh * 16 + si;
    const float fr = (pose[s] == 1) ? 1.f : 0.f;
    float a0 = 0.f, a1 = 0.f, a2 = 0.f, a3 = 0.f;
#pragma unroll
    for (int j = 0; j < 32; ++j) {
      const float4 hv = *(const float4*)&h[s * HID_ + 4 * j];
      const float4 wv = *(const float4*)&wrow[4 * j];
      a0 += hv.x * wv.x;
      a1 += hv.y * wv.y;
      a2 += hv.z * wv.z;
      a3 += hv.w * wv.w;
    }
    const float acc = (a0 + a1) + (a2 + a3);
    const float g = 1.f / (1.f + expf(-(acc + bias)));
    gap[s * C_ + c] = bmean[s * C_ + c] + fr * g;
  }
}

// ---------------------------------------------------------------------------
// Kernel B3: z = gap @ Wl^T + bl.  Same K-along-lanes pattern as mlp1:
// wave = 4s x 16o register tile (o rows clamped at 50, extras discarded).
// grid 128 blocks x 4 waves.
// ---------------------------------------------------------------------------
__global__ __launch_bounds__(256) void logits_k(
    const float* __restrict__ gap, const float* __restrict__ Wl,
    const float* __restrict__ bl, float* __restrict__ z) {
  const int t = threadIdx.x;
  const int lane = t & 63;
  const int w = t >> 6;
  const int s0 = blockIdx.x * 4;
  const int o0 = w * 16;
  float acc[4][16] = {};
  const float* __restrict__ gb = gap + lane;
  const float* __restrict__ wb = Wl + lane;
  for (int kc = 0; kc < 32; ++kc) {
    const int k = kc * 64;
    float p[4], wv[16];
#pragma unroll
    for (int i = 0; i < 4; ++i) p[i] = gb[(s0 + i) * C_ + k];
#pragma unroll
    for (int j = 0; j < 16; ++j) {
      int o = o0 + j;
      if (o > NATTR_ - 1) o = NATTR_ - 1;    // clamp, discard later
      wv[j] = wb[o * C_ + k];
    }
#pragma unroll
    for (int i = 0; i < 4; ++i)
#pragma unroll
      for (int j = 0; j < 16; ++j) acc[i][j] += p[i] * wv[j];
  }
#pragma unroll
  for (int d = 32; d >= 1; d >>= 1)
#pragma unroll
    for (int i = 0; i < 4; ++i)
#pragma unroll
      for (int j = 0; j < 16; ++j) acc[i][j] += __shfl_down(acc[i][j], d);
  if (lane == 0) {
#pragma unroll
    for (int i = 0; i < 4; ++i)
#pragma unroll
      for (int j = 0; j < 16; ++j) {
        const int o = o0 + j;
        if (o < NATTR_)
          z[(s0 + i) * NATTR_ + o] = acc[i][j] + bl[o];
      }
  }
}

// ---------------------------------------------------------------------------
// Kernel C: BatchNorm1d (batch stats, biased variance).
// ---------------------------------------------------------------------------
__global__ __launch_bounds__(512) void bn_kernel(
    const float* __restrict__ z, const float* __restrict__ gamma,
    const float* __restrict__ beta, float* __restrict__ out) {
  const int c = blockIdx.x;
  const int t = threadIdx.x;
  const float v = z[t * NATTR_ + c];
  float a = v, b = v * v;
#pragma unroll
  for (int off = 32; off; off >>= 1) {
    a += __shfl_down(a, off);
    b += __shfl_down(b, off);
  }
  __shared__ float s1[8], s2[8];
  const int w = t >> 6;
  if ((t & 63) == 0) { s1[w] = a; s2[w] = b; }
  __syncthreads();
  __shared__ float mu_s, inv_s;
  if (t == 0) {
    float S = 0.f, Q = 0.f;
#pragma unroll
    for (int i = 0; i < 8; ++i) { S += s1[i]; Q += s2[i]; }
    const float m = S * (1.0f / B_);
    const float var = Q * (1.0f / B_) - m * m;
    mu_s = m;
    inv_s = 1.0f / sqrtf(var + EPS_);
  }
  __syncthreads();
  out[t * NATTR_ + c] = gamma[c] * (v - mu_s) * inv_s + beta[c];
}

// ---------------------------------------------------------------------------
extern "C" void kernel_launch(void* const* d_in, const int* in_sizes, int n_in,
                              void* d_out, int out_size, void* d_ws,
                              size_t ws_size, hipStream_t stream) {
  const float* body = (const float*)d_in[0];
  const float* face = (const float*)d_in[1];
  const int* pose = (const int*)d_in[2];
  const float* A = (const float*)d_in[3];
  const float* W1 = (const float*)d_in[4];
  const float* b1 = (const float*)d_in[5];
  const float* W2 = (const float*)d_in[6];
  const float* b2 = (const float*)d_in[7];
  const float* Wl = (const float*)d_in[8];
  const float* bl = (const float*)d_in[9];
  const float* gamma = (const float*)d_in[10];
  const float* beta = (const float*)d_in[11];
  float* out = (float*)d_out;

  float* ws = (float*)d_ws;
  float* pooled = ws;                       // [512][2048]
  float* bmean = pooled + B_ * C_;          // [512][2048]
  float* h = bmean + B_ * C_;               // [512][128]
  float* gap = h + B_ * HID_;               // [512][2048]
  float* z = gap + B_ * C_;                 // [512][51]

  fused_pool<<<dim3(4096), dim3(256), 0, stream>>>(body, face, A, pooled,
                                                   bmean);
  mlp1<<<dim3(256), dim3(256), 0, stream>>>(pooled, W1, b1, h);
  mlp2<<<dim3(256), dim3(256), 128 * 144 * 4, stream>>>(h, W2, b2, bmean,
                                                        pose, gap);
  logits_k<<<dim3(128), dim3(256), 0, stream>>>(gap, Wl, bl, z);
  bn_kernel<<<dim3(NATTR_), dim3(512), 0, stream>>>(z, gamma, beta, out);
}

// Round 5
// 435.296 us; speedup vs baseline: 1.3983x; 1.1619x over previous
//
#include <hip/hip_runtime.h>
#include <hip/hip_bf16.h>
#include <math.h>

#define B_    512
#define C_    2048
#define HW_   48      // 8*6 spatial
#define HID_  128
#define NATTR_ 51
#define EPS_  1e-5f

typedef float v4f __attribute__((ext_vector_type(4)));  // nontemporal-compatible

// ---------------------------------------------------------------------------
// Kernel A: fused (body*A*face)->spatial max AND spatial mean of body.
// 128 rows/block (8192 blocks), 256 threads, 6 float4/thread/tensor in two
// 3-deep batches.  body/face loads are NONTEMPORAL (ext_vector_type so the
// builtin accepts them): R3 counters showed FETCH=197MB of a 402MB stream
// with the L3-resident half served at only ~1.6 TB/s; forcing HBM streaming
// bypasses the L3-hit throttle.  LDS pitch 13 -> conflict-free reduce.
// feat = body + front*gate (spatial-broadcast) => mean_spatial(feat) =
// mean_spatial(body) + front*gate: second body pass eliminated.
// ---------------------------------------------------------------------------
__global__ __launch_bounds__(256) void fused_pool(
    const float* __restrict__ body, const float* __restrict__ face,
    const float* __restrict__ A, float* __restrict__ pooled,
    float* __restrict__ bmean) {
  __shared__ float smax[128 * 13];
  __shared__ float ssum[128 * 13];
  const int t = threadIdx.x;
  const int base_f4 = blockIdx.x * 1536;     // 8192*1536 < 2^31
  const int a_base = (blockIdx.x & 15) * 1536;
  const v4f* __restrict__ b4 = (const v4f*)body;
  const v4f* __restrict__ f4 = (const v4f*)face;
  const v4f* __restrict__ a4 = (const v4f*)A;
#pragma unroll
  for (int half = 0; half < 2; ++half) {
    v4f vb[3], vf[3], va[3];
#pragma unroll
    for (int j = 0; j < 3; ++j) {
      const int fl = t + 256 * (half * 3 + j);
      vb[j] = __builtin_nontemporal_load(b4 + base_f4 + fl);
      vf[j] = __builtin_nontemporal_load(f4 + base_f4 + fl);
      va[j] = a4[a_base + fl];
    }
#pragma unroll
    for (int j = 0; j < 3; ++j) {
      const int fl = t + 256 * (half * 3 + j);
      const int rl = fl / 12, p = fl % 12;
      const float m0 = vb[j].x * va[j].x * vf[j].x;
      const float m1 = vb[j].y * va[j].y * vf[j].y;
      const float m2 = vb[j].z * va[j].z * vf[j].z;
      const float m3 = vb[j].w * va[j].w * vf[j].w;
      smax[rl * 13 + p] = fmaxf(fmaxf(m0, m1), fmaxf(m2, m3));
      ssum[rl * 13 + p] = (vb[j].x + vb[j].y) + (vb[j].z + vb[j].w);
    }
  }
  __syncthreads();
  if (t < 128) {
    float m = -INFINITY, s = 0.f;
#pragma unroll
    for (int p = 0; p < 12; ++p) {
      m = fmaxf(m, smax[t * 13 + p]);
      s += ssum[t * 13 + p];
    }
    const int row = blockIdx.x * 128 + t;
    pooled[row] = m;
    bmean[row] = s * (1.0f / 48.0f);
  }
}

// ---------------------------------------------------------------------------
// Kernel W: transpose W2 [2048c][128k] -> W2T [128k][2048c] (once, ~1MB).
// 64x64 tiles, LDS pad 65 -> conflict-free both phases.
// ---------------------------------------------------------------------------
__global__ __launch_bounds__(256) void w2t_kernel(
    const float* __restrict__ W2, float* __restrict__ W2T) {
  __shared__ float tile[64][65];
  const int t = threadIdx.x;
  const int kt = blockIdx.x & 1, ct = blockIdx.x >> 1;
  const int c0 = ct * 64, k0 = kt * 64;
  const int x = t & 63, y4 = t >> 6;
#pragma unroll
  for (int i = 0; i < 16; ++i) {
    const int r = y4 + 4 * i;
    tile[r][x] = W2[(c0 + r) * HID_ + k0 + x];   // lanes along k: coalesced
  }
  __syncthreads();
#pragma unroll
  for (int i = 0; i < 16; ++i) {
    const int kk = y4 + 4 * i;
    W2T[(k0 + kk) * C_ + c0 + x] = tile[x][kk];  // lds stride 65: no conflict
  }
}

// ---------------------------------------------------------------------------
// Kernel B1: h = relu(pooled @ W1^T + b1).  K along lanes (coalesced 256B),
// wave tile = 4s x 8o, shfl reduce.  grid 512 blocks x 4 waves (2 blocks/CU).
// ---------------------------------------------------------------------------
__global__ __launch_bounds__(256) void mlp1(
    const float* __restrict__ pooled, const float* __restrict__ W1,
    const float* __restrict__ b1, float* __restrict__ h) {
  const int t = threadIdx.x;
  const int lane = t & 63;
  const int w = t >> 6;
  const int s0 = (blockIdx.x >> 2) * 4;
  const int o0 = ((blockIdx.x & 3) * 4 + w) * 8;
  float acc[4][8] = {};
  const float* __restrict__ pb = pooled + lane;
  const float* __restrict__ wb = W1 + lane;
  for (int kc = 0; kc < 32; ++kc) {
    const int k = kc * 64;
    float p[4], wv[8];
#pragma unroll
    for (int i = 0; i < 4; ++i) p[i] = pb[(s0 + i) * C_ + k];
#pragma unroll
    for (int j = 0; j < 8; ++j) wv[j] = wb[(o0 + j) * C_ + k];
#pragma unroll
    for (int i = 0; i < 4; ++i)
#pragma unroll
      for (int j = 0; j < 8; ++j) acc[i][j] += p[i] * wv[j];
  }
#pragma unroll
  for (int d = 32; d >= 1; d >>= 1)
#pragma unroll
    for (int i = 0; i < 4; ++i)
#pragma unroll
      for (int j = 0; j < 8; ++j) acc[i][j] += __shfl_down(acc[i][j], d);
  if (lane == 0) {
#pragma unroll
    for (int i = 0; i < 4; ++i)
#pragma unroll
      for (int j = 0; j < 8; ++j)
        h[(s0 + i) * HID_ + o0 + j] = fmaxf(acc[i][j] + b1[o0 + j], 0.f);
  }
}

// ---------------------------------------------------------------------------
// Kernel B2: gap = bmean + front*sigmoid(h @ W2^T + b2), via W2T.
// Thread = one c, 4 samples.  W2T column reads coalesced (256B/wave-instr,
// L2-resident); h reads wave-uniform float4 broadcasts.  No LDS at all
// (R3's LDS scheme was an 8-16-way bank conflict on every ds_read_b128).
// grid = 8 c-chunks x 128 s-groups = 1024 blocks.
// ---------------------------------------------------------------------------
__global__ __launch_bounds__(256) void mlp2_t(
    const float* __restrict__ h, const float* __restrict__ W2T,
    const float* __restrict__ b2, const float* __restrict__ bmean,
    const int* __restrict__ pose, float* __restrict__ gap) {
  const int t = threadIdx.x;
  const int c = (blockIdx.x & 7) * 256 + t;
  const int s0 = (blockIdx.x >> 3) * 4;
  float acc[4] = {};
  for (int kq = 0; kq < 32; ++kq) {
    float wv[4];
#pragma unroll
    for (int d = 0; d < 4; ++d) wv[d] = W2T[(4 * kq + d) * C_ + c];
#pragma unroll
    for (int i = 0; i < 4; ++i) {
      const float4 hv = *(const float4*)&h[(s0 + i) * HID_ + 4 * kq];
      acc[i] += hv.x * wv[0] + hv.y * wv[1] + hv.z * wv[2] + hv.w * wv[3];
    }
  }
  const float bias = b2[c];
#pragma unroll
  for (int i = 0; i < 4; ++i) {
    const int s = s0 + i;
    const float fr = (pose[s] == 1) ? 1.f : 0.f;
    const float g = 1.f / (1.f + expf(-(acc[i] + bias)));
    gap[s * C_ + c] = bmean[s * C_ + c] + fr * g;
  }
}

// ---------------------------------------------------------------------------
// Kernel B3: z = gap @ Wl^T + bl.  K along lanes, wave tile = 2s x 13o.
// grid 256 blocks x 4 waves (o covered by 4x13=52 slots, last clamped).
// ---------------------------------------------------------------------------
__global__ __launch_bounds__(256) void logits_k(
    const float* __restrict__ gap, const float* __restrict__ Wl,
    const float* __restrict__ bl, float* __restrict__ z) {
  const int t = threadIdx.x;
  const int lane = t & 63;
  const int w = t >> 6;
  const int s0 = blockIdx.x * 2;
  const int o0 = w * 13;
  float acc[2][13] = {};
  const float* __restrict__ gb = gap + lane;
  const float* __restrict__ wb = Wl + lane;
  for (int kc = 0; kc < 32; ++kc) {
    const int k = kc * 64;
    float p[2], wv[13];
#pragma unroll
    for (int i = 0; i < 2; ++i) p[i] = gb[(s0 + i) * C_ + k];
#pragma unroll
    for (int j = 0; j < 13; ++j) {
      const int o = o0 + j;
      const int orow = (o < NATTR_) ? o : (NATTR_ - 1);
      wv[j] = wb[orow * C_ + k];
    }
#pragma unroll
    for (int i = 0; i < 2; ++i)
#pragma unroll
      for (int j = 0; j < 13; ++j) acc[i][j] += p[i] * wv[j];
  }
#pragma unroll
  for (int d = 32; d >= 1; d >>= 1)
#pragma unroll
    for (int i = 0; i < 2; ++i)
#pragma unroll
      for (int j = 0; j < 13; ++j) acc[i][j] += __shfl_down(acc[i][j], d);
  if (lane == 0) {
#pragma unroll
    for (int i = 0; i < 2; ++i)
#pragma unroll
      for (int j = 0; j < 13; ++j) {
        const int o = o0 + j;
        if (o < NATTR_)
          z[(s0 + i) * NATTR_ + o] = acc[i][j] + bl[o];
      }
  }
}

// ---------------------------------------------------------------------------
// Kernel C: BatchNorm1d (batch stats, biased variance).
// ---------------------------------------------------------------------------
__global__ __launch_bounds__(512) void bn_kernel(
    const float* __restrict__ z, const float* __restrict__ gamma,
    const float* __restrict__ beta, float* __restrict__ out) {
  const int c = blockIdx.x;
  const int t = threadIdx.x;
  const float v = z[t * NATTR_ + c];
  float a = v, b = v * v;
#pragma unroll
  for (int off = 32; off; off >>= 1) {
    a += __shfl_down(a, off);
    b += __shfl_down(b, off);
  }
  __shared__ float s1[8], s2[8];
  const int w = t >> 6;
  if ((t & 63) == 0) { s1[w] = a; s2[w] = b; }
  __syncthreads();
  __shared__ float mu_s, inv_s;
  if (t == 0) {
    float S = 0.f, Q = 0.f;
#pragma unroll
    for (int i = 0; i < 8; ++i) { S += s1[i]; Q += s2[i]; }
    const float m = S * (1.0f / B_);
    const float var = Q * (1.0f / B_) - m * m;
    mu_s = m;
    inv_s = 1.0f / sqrtf(var + EPS_);
  }
  __syncthreads();
  out[t * NATTR_ + c] = gamma[c] * (v - mu_s) * inv_s + beta[c];
}

// ---------------------------------------------------------------------------
extern "C" void kernel_launch(void* const* d_in, const int* in_sizes, int n_in,
                              void* d_out, int out_size, void* d_ws,
                              size_t ws_size, hipStream_t stream) {
  const float* body = (const float*)d_in[0];
  const float* face = (const float*)d_in[1];
  const int* pose = (const int*)d_in[2];
  const float* A = (const float*)d_in[3];
  const float* W1 = (const float*)d_in[4];
  const float* b1 = (const float*)d_in[5];
  const float* W2 = (const float*)d_in[6];
  const float* b2 = (const float*)d_in[7];
  const float* Wl = (const float*)d_in[8];
  const float* bl = (const float*)d_in[9];
  const float* gamma = (const float*)d_in[10];
  const float* beta = (const float*)d_in[11];
  float* out = (float*)d_out;

  float* ws = (float*)d_ws;
  float* pooled = ws;                       // [512][2048]
  float* bmean = pooled + B_ * C_;          // [512][2048]
  float* h = bmean + B_ * C_;               // [512][128]
  float* gap = h + B_ * HID_;               // [512][2048]
  float* z = gap + B_ * C_;                 // [512][51]
  float* W2T = z + B_ * NATTR_;             // [128][2048]

  w2t_kernel<<<dim3(64), dim3(256), 0, stream>>>(W2, W2T);
  fused_pool<<<dim3(8192), dim3(256), 0, stream>>>(body, face, A, pooled,
                                                   bmean);
  mlp1<<<dim3(512), dim3(256), 0, stream>>>(pooled, W1, b1, h);
  mlp2_t<<<dim3(1024), dim3(256), 0, stream>>>(h, W2T, b2, bmean, pose, gap);
  logits_k<<<dim3(256), dim3(256), 0, stream>>>(gap, Wl, bl, z);
  bn_kernel<<<dim3(NATTR_), dim3(512), 0, stream>>>(z, gamma, beta, out);
}